// Round 1
// baseline (12296.767 us; speedup 1.0000x reference)
//
#include <hip/hip_runtime.h>
#include <stdint.h>

#define BB 64
#define TT 512
#define DD 1024
#define HH 1024

typedef float f32x4 __attribute__((ext_vector_type(4)));
typedef short s16x8 __attribute__((ext_vector_type(8)));
typedef unsigned short ushort_t;
typedef unsigned int uint32;

#define MFMA(a, b, c) __builtin_amdgcn_mfma_f32_16x16x32_bf16((a), (b), (c), 0, 0, 0)

__device__ __forceinline__ ushort_t f2bf(float f) {
    uint32 u = __float_as_uint(f);
    u += 0x7FFFu + ((u >> 16) & 1u);   // RNE
    return (ushort_t)(u >> 16);
}
__device__ __forceinline__ float bf2f(ushort_t h) {
    return __uint_as_float(((uint32)h) << 16);
}
__device__ __forceinline__ void cv8(const float4& v0, const float4& v1, s16x8& hi, s16x8& lo) {
    float a0 = v0.x, a1 = v0.y, a2 = v0.z, a3 = v0.w;
    float a4 = v1.x, a5 = v1.y, a6 = v1.z, a7 = v1.w;
#define SPL(J, V) { ushort_t h = f2bf(V); hi[J] = (short)h; lo[J] = (short)f2bf((V) - bf2f(h)); }
    SPL(0, a0) SPL(1, a1) SPL(2, a2) SPL(3, a3)
    SPL(4, a4) SPL(5, a5) SPL(6, a6) SPL(7, a7)
#undef SPL
}

// ---------------------------------------------------------------------------
// K1: pre0[b*T+t][n] = x[b*T+t][:] . Wi0[n][:] + bi0[n]     (3-pass bf16 split)
// Output written into d_out (same layout as out[b][t][n]); overwritten later.
// ---------------------------------------------------------------------------
__global__ __launch_bounds__(256) void k_pre0(
    const float* __restrict__ x, const float* __restrict__ Wi0,
    const float* __restrict__ bi0, float* __restrict__ pre0) {
    __shared__ ushort_t Ah[4096], Al[4096], Bh[4096], Bl[4096];  // 32 KB
    const int bid = blockIdx.x;
    const int mt = bid >> 3, nt = bid & 7;
    const int tid = threadIdx.x;
    const int lane = tid & 63, wave = tid >> 6;
    const int wm = (wave >> 1) * 64, wn = (wave & 1) * 64;
    const int lrow = lane & 15, lg = lane >> 4;

    const float* Ab = x + (size_t)mt * 128 * 1024;
    const float* Bb = Wi0 + (size_t)nt * 128 * 1024;

    f32x4 acc[4][4] = {};

    for (int kt = 0; kt < 32; ++kt) {
        __syncthreads();
        // stage 128x32 fp32 of A and B -> hi/lo bf16 planes (swizzled)
#pragma unroll
        for (int g = 0; g < 2; ++g) {
            int gid = g * 256 + tid;           // 512 granules of 8 elems
            int row = gid >> 2, kc = gid & 3;
            int loc = ((kc ^ ((row >> 1) & 3)) << 3) + (row << 5);
            const float* sa = Ab + (size_t)row * 1024 + kt * 32 + kc * 8;
            const float* sb = Bb + (size_t)row * 1024 + kt * 32 + kc * 8;
            float4 a0 = *(const float4*)sa, a1 = *(const float4*)(sa + 4);
            float4 b0 = *(const float4*)sb, b1 = *(const float4*)(sb + 4);
            s16x8 vh, vl;
            cv8(a0, a1, vh, vl);
            *(s16x8*)(Ah + loc) = vh; *(s16x8*)(Al + loc) = vl;
            cv8(b0, b1, vh, vl);
            *(s16x8*)(Bh + loc) = vh; *(s16x8*)(Bl + loc) = vl;
        }
        __syncthreads();
        s16x8 fah[4], fal[4], fbh[4], fbl[4];
#pragma unroll
        for (int f = 0; f < 4; ++f) {
            int ra = wm + f * 16 + lrow;
            int la = ((lg ^ ((ra >> 1) & 3)) << 3) + (ra << 5);
            fah[f] = *(const s16x8*)(Ah + la);
            fal[f] = *(const s16x8*)(Al + la);
            int rb = wn + f * 16 + lrow;
            int lb = ((lg ^ ((rb >> 1) & 3)) << 3) + (rb << 5);
            fbh[f] = *(const s16x8*)(Bh + lb);
            fbl[f] = *(const s16x8*)(Bl + lb);
        }
        // pass-major order: 16-MFMA dep distance per accumulator
#pragma unroll
        for (int mf = 0; mf < 4; ++mf)
#pragma unroll
            for (int nf = 0; nf < 4; ++nf)
                acc[mf][nf] = MFMA(fah[mf], fbh[nf], acc[mf][nf]);
#pragma unroll
        for (int mf = 0; mf < 4; ++mf)
#pragma unroll
            for (int nf = 0; nf < 4; ++nf)
                acc[mf][nf] = MFMA(fah[mf], fbl[nf], acc[mf][nf]);
#pragma unroll
        for (int mf = 0; mf < 4; ++mf)
#pragma unroll
            for (int nf = 0; nf < 4; ++nf)
                acc[mf][nf] = MFMA(fal[mf], fbh[nf], acc[mf][nf]);
    }
#pragma unroll
    for (int nf = 0; nf < 4; ++nf) {
        int col = nt * 128 + wn + nf * 16 + lrow;
        float bc = bi0[col];
#pragma unroll
        for (int mf = 0; mf < 4; ++mf)
#pragma unroll
            for (int r = 0; r < 4; ++r) {
                int row = mt * 128 + wm + mf * 16 + lg * 4 + r;
                pre0[(size_t)row * 1024 + col] = acc[mf][nf][r] + bc;
            }
    }
}

// ---------------------------------------------------------------------------
// K2: persistent 2-layer RNN. 192 WGs (64 L0 + 128 L1), 513 phases.
// State planes in ws (ushort): [parity(2)][h0hi,h0lo,h1hi,h1lo][64][1024]
// ---------------------------------------------------------------------------
#define PL(par, which) (st + (size_t)((((par) << 2) + (which))) * 65536)

__global__ __launch_bounds__(256, 1) void k_rnn(
    const float* __restrict__ Wr0, const float* __restrict__ Wi1,
    const float* __restrict__ Wr1, const float* __restrict__ bi1,
    const float* __restrict__ bm0, const float* __restrict__ bm1,
    float* __restrict__ dout, ushort_t* __restrict__ st, uint32* __restrict__ bar) {
    extern __shared__ __align__(16) char smem[];
    ushort_t* Bh = (ushort_t*)smem;          // 64 KB hi weights
    ushort_t* Bl = Bh + 32768;               // 64 KB lo weights
    float* sred = (float*)(smem + 131072);   // 4 KB k-half reduce scratch
    uint32* grp = bar;                       // 6 group counters, 128B apart
    uint32* root = bar + 256;
    uint32* flag = bar + 288;

    const int bid = blockIdx.x;
    const bool isL0 = bid < 64;
    const int tid = threadIdx.x, lane = tid & 63, wave = tid >> 6;
    const int mq = wave >> 1, kh = wave & 1;
    const int lrow = lane & 15, lg = lane >> 4, lk8 = lg << 3;
    int mh, nt;
    if (isL0) { mh = bid & 1; nt = bid >> 1; }          // nt: 0..31 (32-col tiles)
    else      { int id = bid - 64; mh = id & 1; nt = id >> 1; }  // nt: 0..63 (16-col)

    // ---- stage constant weights into LDS (hi/lo bf16, XOR-swizzled) ----
    if (isL0) {
        const float* W = Wr0 + (size_t)nt * 32 * 1024;
        for (int i = 0; i < 16; ++i) {
            int gid = i * 256 + tid;               // 4096 granules: [32 rows][128 gk]
            int row = gid >> 7, gk = gid & 127;
            const float* src = W + (size_t)row * 1024 + gk * 8;
            float4 v0 = *(const float4*)src, v1 = *(const float4*)(src + 4);
            s16x8 vh, vl;
            cv8(v0, v1, vh, vl);
            int loc = ((gk ^ (row & 7)) << 3) + (row << 10);
            *(s16x8*)(Bh + loc) = vh; *(s16x8*)(Bl + loc) = vl;
        }
    } else {
        for (int i = 0; i < 16; ++i) {
            int gid = i * 256 + tid;               // 4096 granules: [16 rows][256 gk]
            int row = gid >> 8, gk = gid & 255;
            const float* src = (gk < 128)
                ? Wi1 + (size_t)(nt * 16 + row) * 1024 + gk * 8
                : Wr1 + (size_t)(nt * 16 + row) * 1024 + (gk - 128) * 8;
            float4 v0 = *(const float4*)src, v1 = *(const float4*)(src + 4);
            s16x8 vh, vl;
            cv8(v0, v1, vh, vl);
            int loc = ((gk ^ (row & 7)) << 3) + (row << 11);
            *(s16x8*)(Bh + loc) = vh; *(s16x8*)(Bl + loc) = vl;
        }
    }
    __syncthreads();

    // hoisted per-lane constants (finalizing waves only)
    float cA = 0.f, cB = 0.f, cI = 0.f;
    if (kh == 0) {
        if (isL0) { cA = bm0[nt * 32 + lrow]; cB = bm0[nt * 32 + 16 + lrow]; }
        else      { int col = nt * 16 + lrow; cI = bi1[col]; cB = bm1[col]; }
    }

    float* outp = dout;
    const float* pre0 = dout;
    float* fst = dout + (size_t)BB * TT * HH;

    const int mrow = mh * 32 + mq * 16 + lrow;
    const int brow = mh * 32 + mq * 16 + lg * 4;

#pragma unroll 1
    for (int p = 0; p <= 512; ++p) {
        const int parW = p & 1, parR = parW ^ 1;
        if (isL0) {
            if (p <= 511) {
                const ushort_t* Ahp = PL(parR, 0) + mrow * 1024 + kh * 512 + lk8;
                const ushort_t* Alp = PL(parR, 1) + mrow * 1024 + kh * 512 + lk8;
                float pf0[4], pf1[4];
                if (kh == 0) {       // prefetch pre0 (hidden under k-loop)
#pragma unroll
                    for (int r = 0; r < 4; ++r) {
                        pf0[r] = pre0[((size_t)(brow + r) * 512 + p) * 1024 + nt * 32 + lrow];
                        pf1[r] = pre0[((size_t)(brow + r) * 512 + p) * 1024 + nt * 32 + 16 + lrow];
                    }
                }
                f32x4 a00{}, a01{}, a02{}, a10{}, a11{}, a12{};
                s16x8 ah[4], al[4];
#pragma unroll
                for (int i = 0; i < 4; ++i) {
                    ah[i] = *(const s16x8*)(Ahp + i * 32);
                    al[i] = *(const s16x8*)(Alp + i * 32);
                }
#pragma unroll
                for (int blk = 0; blk < 4; ++blk) {
                    s16x8 nh[4], nl[4];
                    if (blk < 3) {
#pragma unroll
                        for (int i = 0; i < 4; ++i) {
                            nh[i] = *(const s16x8*)(Ahp + (blk * 4 + 4 + i) * 32);
                            nl[i] = *(const s16x8*)(Alp + (blk * 4 + 4 + i) * 32);
                        }
                    }
#pragma unroll
                    for (int i = 0; i < 4; ++i) {
                        int ks = blk * 4 + i;
                        int gkb = kh * 64 + ks * 4 + lg;
                        int r0w = lrow, r1w = 16 + lrow;
                        int l0 = ((gkb ^ (r0w & 7)) << 3) + (r0w << 10);
                        int l1 = ((gkb ^ (r1w & 7)) << 3) + (r1w << 10);
                        s16x8 b0h = *(const s16x8*)(Bh + l0), b0l = *(const s16x8*)(Bl + l0);
                        s16x8 b1h = *(const s16x8*)(Bh + l1), b1l = *(const s16x8*)(Bl + l1);
                        a00 = MFMA(ah[i], b0h, a00); a10 = MFMA(ah[i], b1h, a10);
                        a01 = MFMA(ah[i], b0l, a01); a11 = MFMA(ah[i], b1l, a11);
                        a02 = MFMA(al[i], b0h, a02); a12 = MFMA(al[i], b1h, a12);
                    }
                    if (blk < 3) {
#pragma unroll
                        for (int i = 0; i < 4; ++i) { ah[i] = nh[i]; al[i] = nl[i]; }
                    }
                }
                f32x4 r0 = a00 + a01 + a02, r1 = a10 + a11 + a12;
                if (kh == 1) {
#pragma unroll
                    for (int r = 0; r < 4; ++r) {
                        sred[(mq * 2 + 0) * 256 + (lg * 4 + r) * 16 + lrow] = r0[r];
                        sred[(mq * 2 + 1) * 256 + (lg * 4 + r) * 16 + lrow] = r1[r];
                    }
                }
                __syncthreads();
                if (kh == 0) {
                    ushort_t* Hh = PL(parW, 0);
                    ushort_t* Hl = PL(parW, 1);
#pragma unroll
                    for (int nf = 0; nf < 2; ++nf) {
                        int col = nt * 32 + nf * 16 + lrow;
                        float bm = nf ? cB : cA;
#pragma unroll
                        for (int r = 0; r < 4; ++r) {
                            float z = (nf ? r1[r] : r0[r])
                                      + sred[(mq * 2 + nf) * 256 + (lg * 4 + r) * 16 + lrow]
                                      + (nf ? pf1[r] : pf0[r]);
                            float t1 = fmaxf(fabsf(z) + bm, 0.f);
                            float h = copysignf(t1, z);      // modrelu
                            int b = brow + r;
                            ushort_t hi = f2bf(h);
                            Hh[b * 1024 + col] = hi;
                            Hl[b * 1024 + col] = f2bf(h - bf2f(hi));
                            if (p == 511) fst[(size_t)b * 1024 + col] = h;
                        }
                    }
                }
            }
        } else {
            if (p >= 1) {
                const int t = p - 1;
                const ushort_t* Ahp;
                const ushort_t* Alp;
                if (kh == 0) { Ahp = PL(parR, 0) + mrow * 1024 + lk8; Alp = PL(parR, 1) + mrow * 1024 + lk8; }
                else         { Ahp = PL(parW, 2) + mrow * 1024 + lk8; Alp = PL(parW, 3) + mrow * 1024 + lk8; }
                f32x4 a0{}, a1{}, a2{};
                s16x8 ah[4], al[4];
#pragma unroll
                for (int i = 0; i < 4; ++i) {
                    ah[i] = *(const s16x8*)(Ahp + i * 32);
                    al[i] = *(const s16x8*)(Alp + i * 32);
                }
#pragma unroll
                for (int blk = 0; blk < 8; ++blk) {
                    s16x8 nh[4], nl[4];
                    if (blk < 7) {
#pragma unroll
                        for (int i = 0; i < 4; ++i) {
                            nh[i] = *(const s16x8*)(Ahp + (blk * 4 + 4 + i) * 32);
                            nl[i] = *(const s16x8*)(Alp + (blk * 4 + 4 + i) * 32);
                        }
                    }
#pragma unroll
                    for (int i = 0; i < 4; ++i) {
                        int ks = blk * 4 + i;
                        int gkb = kh * 128 + ks * 4 + lg;
                        int loc = ((gkb ^ (lrow & 7)) << 3) + (lrow << 11);
                        s16x8 bh = *(const s16x8*)(Bh + loc), bl = *(const s16x8*)(Bl + loc);
                        a0 = MFMA(ah[i], bh, a0);
                        a1 = MFMA(ah[i], bl, a1);
                        a2 = MFMA(al[i], bh, a2);
                    }
                    if (blk < 7) {
#pragma unroll
                        for (int i = 0; i < 4; ++i) { ah[i] = nh[i]; al[i] = nl[i]; }
                    }
                }
                f32x4 rr = a0 + a1 + a2;
                if (kh == 1) {
#pragma unroll
                    for (int r = 0; r < 4; ++r)
                        sred[mq * 256 + (lg * 4 + r) * 16 + lrow] = rr[r];
                }
                __syncthreads();
                if (kh == 0) {
                    int col = nt * 16 + lrow;
                    ushort_t* Hh = PL(parR, 2);
                    ushort_t* Hl = PL(parR, 3);
#pragma unroll
                    for (int r = 0; r < 4; ++r) {
                        float z = rr[r] + sred[mq * 256 + (lg * 4 + r) * 16 + lrow] + cI;
                        float t1 = fmaxf(fabsf(z) + cB, 0.f);
                        float h = copysignf(t1, z);
                        int b = brow + r;
                        ushort_t hi = f2bf(h);
                        Hh[b * 1024 + col] = hi;
                        Hl[b * 1024 + col] = f2bf(h - bf2f(hi));
                        outp[((size_t)b * 512 + t) * 1024 + col] = h;
                        if (t == 511) fst[65536 + (size_t)b * 1024 + col] = h;
                    }
                }
            }
        }
        // ---- grid barrier (two-level, device-scope) ----
        __syncthreads();
        if (tid == 0) {
            __threadfence();
            int g = bid >> 5;   // 6 groups of 32
            uint32 lgc = __hip_atomic_fetch_add(&grp[g * 32], 1u, __ATOMIC_ACQ_REL, __HIP_MEMORY_SCOPE_AGENT);
            bool released = false;
            if (lgc == (uint32)(p * 32 + 31)) {
                uint32 rc = __hip_atomic_fetch_add(root, 1u, __ATOMIC_ACQ_REL, __HIP_MEMORY_SCOPE_AGENT);
                if (rc == (uint32)(p * 6 + 5)) {
                    __hip_atomic_store(flag, (uint32)(p + 1), __ATOMIC_RELEASE, __HIP_MEMORY_SCOPE_AGENT);
                    released = true;
                }
            }
            if (!released) {
                while (__hip_atomic_load(flag, __ATOMIC_RELAXED, __HIP_MEMORY_SCOPE_AGENT) <= (uint32)p)
                    __builtin_amdgcn_s_sleep(1);
            }
            __threadfence();
        }
        __syncthreads();
    }
}

// ---------------------------------------------------------------------------
extern "C" void kernel_launch(void* const* d_in, const int* in_sizes, int n_in,
                              void* d_out, int out_size, void* d_ws, size_t ws_size,
                              hipStream_t stream) {
    const float* x   = (const float*)d_in[0];
    const float* Wi0 = (const float*)d_in[1];
    const float* bi0 = (const float*)d_in[2];
    const float* Wr0 = (const float*)d_in[3];
    const float* bm0 = (const float*)d_in[4];
    const float* Wi1 = (const float*)d_in[5];
    const float* bi1 = (const float*)d_in[6];
    const float* Wr1 = (const float*)d_in[7];
    const float* bm1 = (const float*)d_in[8];
    float* out = (float*)d_out;

    ushort_t* st = (ushort_t*)d_ws;                       // 8 planes * 128 KB = 1 MB
    uint32* bar = (uint32*)((char*)d_ws + (1 << 20));     // barrier state

    // zero the parity-1 state planes (h[-1] = 0) and the barrier counters
    hipMemsetAsync((char*)d_ws + (size_t)4 * 65536 * 2, 0, (size_t)4 * 65536 * 2, stream);
    hipMemsetAsync(bar, 0, 2048, stream);

    // allow 132 KB dynamic LDS (idempotent; safe under graph capture)
    hipFuncSetAttribute((const void*)k_rnn, hipFuncAttributeMaxDynamicSharedMemorySize, 135168);

    // K1: input projection for all timesteps, into d_out (doubles as pre0)
    k_pre0<<<2048, 256, 0, stream>>>(x, Wi0, bi0, out);

    // K2: persistent recurrent kernel (192 WGs, all co-resident: 132KB LDS -> 1/CU)
    k_rnn<<<192, 256, 135168, stream>>>(Wr0, Wi1, Wr1, bi1, bm0, bm1, out, st, bar);
}

// Round 2
// 5598.723 us; speedup vs baseline: 2.1964x; 2.1964x over previous
//
#include <hip/hip_runtime.h>
#include <stdint.h>

#define BB 64
#define TT 512
#define DD 1024
#define HH 1024

typedef float f32x4 __attribute__((ext_vector_type(4)));
typedef short s16x8 __attribute__((ext_vector_type(8)));
typedef unsigned short ushort_t;
typedef unsigned int uint32;

#define MFMA(a, b, c) __builtin_amdgcn_mfma_f32_16x16x32_bf16((a), (b), (c), 0, 0, 0)

__device__ __forceinline__ ushort_t f2bf(float f) {
    uint32 u = __float_as_uint(f);
    u += 0x7FFFu + ((u >> 16) & 1u);   // RNE
    return (ushort_t)(u >> 16);
}
__device__ __forceinline__ float bf2f(ushort_t h) {
    return __uint_as_float(((uint32)h) << 16);
}
__device__ __forceinline__ void cv8(const float4& v0, const float4& v1, s16x8& hi, s16x8& lo) {
    float a0 = v0.x, a1 = v0.y, a2 = v0.z, a3 = v0.w;
    float a4 = v1.x, a5 = v1.y, a6 = v1.z, a7 = v1.w;
#define SPL(J, V) { ushort_t h = f2bf(V); hi[J] = (short)h; lo[J] = (short)f2bf((V) - bf2f(h)); }
    SPL(0, a0) SPL(1, a1) SPL(2, a2) SPL(3, a3)
    SPL(4, a4) SPL(5, a5) SPL(6, a6) SPL(7, a7)
#undef SPL
}

// ---- coherent (IF$-scope) memory ops: bypass L1/L2, no cache-wide fences ----
#define GLD_(dst, base, OFF) \
    asm volatile("global_load_dwordx4 %0, %1, off offset:" #OFF " sc0 sc1" \
                 : "=v"(dst) : "v"(base) : "memory")
#define GLD(dst, base, OFF) GLD_(dst, base, OFF)

#define ISSUE8(H, L, bh, bl) \
    GLD(H[0], bh, 0);   GLD(H[1], bh, 64);  GLD(H[2], bh, 128); GLD(H[3], bh, 192); \
    GLD(H[4], bh, 256); GLD(H[5], bh, 320); GLD(H[6], bh, 384); GLD(H[7], bh, 448); \
    GLD(L[0], bl, 0);   GLD(L[1], bl, 64);  GLD(L[2], bl, 128); GLD(L[3], bl, 192); \
    GLD(L[4], bl, 256); GLD(L[5], bl, 320); GLD(L[6], bl, 384); GLD(L[7], bl, 448)

#define WAITB_(N, H, L) \
    asm volatile("s_waitcnt vmcnt(" #N ")" \
        : "+v"(H[0]),"+v"(H[1]),"+v"(H[2]),"+v"(H[3]),"+v"(H[4]),"+v"(H[5]),"+v"(H[6]),"+v"(H[7]), \
          "+v"(L[0]),"+v"(L[1]),"+v"(L[2]),"+v"(L[3]),"+v"(L[4]),"+v"(L[5]),"+v"(L[6]),"+v"(L[7]) \
        :: "memory"); \
    __builtin_amdgcn_sched_barrier(0)
#define WAITB(N, H, L) WAITB_(N, H, L)

#define STS(ptr, val) \
    asm volatile("global_store_short %0, %1, off sc0 sc1" \
                 :: "v"(ptr), "v"((uint32)(val)) : "memory")

// ---------------------------------------------------------------------------
// K1: pre0[b*T+t][n] = x[b*T+t][:] . Wi0[n][:] + bi0[n]     (3-pass bf16 split)
// Output written into d_out (same layout as out[b][t][n]); overwritten later.
// ---------------------------------------------------------------------------
__global__ __launch_bounds__(256) void k_pre0(
    const float* __restrict__ x, const float* __restrict__ Wi0,
    const float* __restrict__ bi0, float* __restrict__ pre0) {
    __shared__ ushort_t Ah[4096], Al[4096], Bh[4096], Bl[4096];  // 32 KB
    const int bid = blockIdx.x;
    const int mt = bid >> 3, nt = bid & 7;
    const int tid = threadIdx.x;
    const int lane = tid & 63, wave = tid >> 6;
    const int wm = (wave >> 1) * 64, wn = (wave & 1) * 64;
    const int lrow = lane & 15, lg = lane >> 4;

    const float* Ab = x + (size_t)mt * 128 * 1024;
    const float* Bb = Wi0 + (size_t)nt * 128 * 1024;

    f32x4 acc[4][4] = {};

    for (int kt = 0; kt < 32; ++kt) {
        __syncthreads();
#pragma unroll
        for (int g = 0; g < 2; ++g) {
            int gid = g * 256 + tid;
            int row = gid >> 2, kc = gid & 3;
            int loc = ((kc ^ ((row >> 1) & 3)) << 3) + (row << 5);
            const float* sa = Ab + (size_t)row * 1024 + kt * 32 + kc * 8;
            const float* sb = Bb + (size_t)row * 1024 + kt * 32 + kc * 8;
            float4 a0 = *(const float4*)sa, a1 = *(const float4*)(sa + 4);
            float4 b0 = *(const float4*)sb, b1 = *(const float4*)(sb + 4);
            s16x8 vh, vl;
            cv8(a0, a1, vh, vl);
            *(s16x8*)(Ah + loc) = vh; *(s16x8*)(Al + loc) = vl;
            cv8(b0, b1, vh, vl);
            *(s16x8*)(Bh + loc) = vh; *(s16x8*)(Bl + loc) = vl;
        }
        __syncthreads();
        s16x8 fah[4], fal[4], fbh[4], fbl[4];
#pragma unroll
        for (int f = 0; f < 4; ++f) {
            int ra = wm + f * 16 + lrow;
            int la = ((lg ^ ((ra >> 1) & 3)) << 3) + (ra << 5);
            fah[f] = *(const s16x8*)(Ah + la);
            fal[f] = *(const s16x8*)(Al + la);
            int rb = wn + f * 16 + lrow;
            int lb = ((lg ^ ((rb >> 1) & 3)) << 3) + (rb << 5);
            fbh[f] = *(const s16x8*)(Bh + lb);
            fbl[f] = *(const s16x8*)(Bl + lb);
        }
#pragma unroll
        for (int mf = 0; mf < 4; ++mf)
#pragma unroll
            for (int nf = 0; nf < 4; ++nf)
                acc[mf][nf] = MFMA(fah[mf], fbh[nf], acc[mf][nf]);
#pragma unroll
        for (int mf = 0; mf < 4; ++mf)
#pragma unroll
            for (int nf = 0; nf < 4; ++nf)
                acc[mf][nf] = MFMA(fah[mf], fbl[nf], acc[mf][nf]);
#pragma unroll
        for (int mf = 0; mf < 4; ++mf)
#pragma unroll
            for (int nf = 0; nf < 4; ++nf)
                acc[mf][nf] = MFMA(fal[mf], fbh[nf], acc[mf][nf]);
    }
#pragma unroll
    for (int nf = 0; nf < 4; ++nf) {
        int col = nt * 128 + wn + nf * 16 + lrow;
        float bc = bi0[col];
#pragma unroll
        for (int mf = 0; mf < 4; ++mf)
#pragma unroll
            for (int r = 0; r < 4; ++r) {
                int row = mt * 128 + wm + mf * 16 + lg * 4 + r;
                pre0[(size_t)row * 1024 + col] = acc[mf][nf][r] + bc;
            }
    }
}

// ---------------------------------------------------------------------------
// K2: persistent 2-layer RNN. 192 WGs (64 L0 + 128 L1), 513 phases.
// State planes in ws (ushort): [parity(2)][h0hi,h0lo,h1hi,h1lo][64][1024]
// Communication via sc0/sc1 (IF$-coherent) ops; barrier is fence-free.
// ---------------------------------------------------------------------------
#define PL(par, which) (st + (size_t)((((par) << 2) + (which))) * 65536)

// inner-chunk compute macros (8 k-steps from a register bank)
#define L0_CHUNK(H, L, KB) \
_Pragma("unroll") \
    for (int i = 0; i < 8; ++i) { \
        int gkb = kh * 64 + ((KB) + i) * 4 + lg; \
        int l0 = ((gkb ^ (lrow & 7)) << 3) + (lrow << 10); \
        int l1b = ((gkb ^ (lrow & 7)) << 3) + ((16 + lrow) << 10); \
        s16x8 b0h = *(const s16x8*)(Bh + l0), b0l = *(const s16x8*)(Bl + l0); \
        s16x8 b1h = *(const s16x8*)(Bh + l1b), b1l = *(const s16x8*)(Bl + l1b); \
        a00 = MFMA(H[i], b0h, a00); a10 = MFMA(H[i], b1h, a10); \
        a01 = MFMA(H[i], b0l, a01); a11 = MFMA(H[i], b1l, a11); \
        a02 = MFMA(L[i], b0h, a02); a12 = MFMA(L[i], b1h, a12); \
    }

#define L1_CHUNK(H, L, KB) \
_Pragma("unroll") \
    for (int i = 0; i < 8; ++i) { \
        int gkb = kh * 128 + ((KB) + i) * 4 + lg; \
        int loc = ((gkb ^ (lrow & 7)) << 3) + (lrow << 11); \
        s16x8 bh = *(const s16x8*)(Bh + loc), bl = *(const s16x8*)(Bl + loc); \
        a0 = MFMA(H[i], bh, a0); \
        a1 = MFMA(H[i], bl, a1); \
        a2 = MFMA(L[i], bh, a2); \
    }

__global__ __launch_bounds__(256, 1) void k_rnn(
    const float* __restrict__ Wr0, const float* __restrict__ Wi1,
    const float* __restrict__ Wr1, const float* __restrict__ bi1,
    const float* __restrict__ bm0, const float* __restrict__ bm1,
    float* __restrict__ dout, ushort_t* __restrict__ st, uint32* __restrict__ bar) {
    extern __shared__ __align__(16) char smem[];
    ushort_t* Bh = (ushort_t*)smem;          // 64 KB hi weights
    ushort_t* Bl = Bh + 32768;               // 64 KB lo weights
    float* sred = (float*)(smem + 131072);   // 4 KB k-half reduce scratch
    uint32* grp = bar;                       // 6 group counters, 128B apart
    uint32* root = bar + 256;
    uint32* flag = bar + 288;

    const int bid = blockIdx.x;
    const bool isL0 = bid < 64;
    const int tid = threadIdx.x, lane = tid & 63, wave = tid >> 6;
    const int mq = wave >> 1, kh = wave & 1;
    const int lrow = lane & 15, lg = lane >> 4, lk8 = lg << 3;
    int mh, nt;
    if (isL0) { mh = bid & 1; nt = bid >> 1; }
    else      { int id = bid - 64; mh = id & 1; nt = id >> 1; }

    // ---- stage constant weights into LDS (hi/lo bf16, XOR-swizzled) ----
    if (isL0) {
        const float* W = Wr0 + (size_t)nt * 32 * 1024;
        for (int i = 0; i < 16; ++i) {
            int gid = i * 256 + tid;
            int row = gid >> 7, gk = gid & 127;
            const float* src = W + (size_t)row * 1024 + gk * 8;
            float4 v0 = *(const float4*)src, v1 = *(const float4*)(src + 4);
            s16x8 vh, vl;
            cv8(v0, v1, vh, vl);
            int loc = ((gk ^ (row & 7)) << 3) + (row << 10);
            *(s16x8*)(Bh + loc) = vh; *(s16x8*)(Bl + loc) = vl;
        }
    } else {
        for (int i = 0; i < 16; ++i) {
            int gid = i * 256 + tid;
            int row = gid >> 8, gk = gid & 255;
            const float* src = (gk < 128)
                ? Wi1 + (size_t)(nt * 16 + row) * 1024 + gk * 8
                : Wr1 + (size_t)(nt * 16 + row) * 1024 + (gk - 128) * 8;
            float4 v0 = *(const float4*)src, v1 = *(const float4*)(src + 4);
            s16x8 vh, vl;
            cv8(v0, v1, vh, vl);
            int loc = ((gk ^ (row & 7)) << 3) + (row << 11);
            *(s16x8*)(Bh + loc) = vh; *(s16x8*)(Bl + loc) = vl;
        }
    }
    __syncthreads();

    float cA = 0.f, cB = 0.f, cI = 0.f;
    if (kh == 0) {
        if (isL0) { cA = bm0[nt * 32 + lrow]; cB = bm0[nt * 32 + 16 + lrow]; }
        else      { int col = nt * 16 + lrow; cI = bi1[col]; cB = bm1[col]; }
    }

    float* outp = dout;
    const float* pre0 = dout;
    float* fst = dout + (size_t)BB * TT * HH;

    const int mrow = mh * 32 + mq * 16 + lrow;
    const int brow = mh * 32 + mq * 16 + lg * 4;

#pragma unroll 1
    for (int p = 0; p <= 512; ++p) {
        const int parW = p & 1, parR = parW ^ 1;
        if (isL0) {
            if (p <= 511) {
                const ushort_t* Ahp = PL(parR, 0) + mrow * 1024 + kh * 512 + lk8;
                const ushort_t* Alp = PL(parR, 1) + mrow * 1024 + kh * 512 + lk8;
                float pf0[4], pf1[4];
                if (kh == 0) {       // plain cached loads, hidden under k-loop
#pragma unroll
                    for (int r = 0; r < 4; ++r) {
                        pf0[r] = pre0[((size_t)(brow + r) * 512 + p) * 1024 + nt * 32 + lrow];
                        pf1[r] = pre0[((size_t)(brow + r) * 512 + p) * 1024 + nt * 32 + 16 + lrow];
                    }
                }
                s16x8 A0h[8], A0l[8], A1h[8], A1l[8];
                ISSUE8(A0h, A0l, Ahp, Alp);
                ISSUE8(A1h, A1l, Ahp + 256, Alp + 256);
                f32x4 a00{}, a01{}, a02{}, a10{}, a11{}, a12{};
                WAITB(16, A0h, A0l);       // chunk0 ready (newest 16 = chunk1)
                L0_CHUNK(A0h, A0l, 0)
                WAITB(0, A1h, A1l);        // chunk1 ready
                L0_CHUNK(A1h, A1l, 8)
                f32x4 r0 = a00 + a01 + a02, r1 = a10 + a11 + a12;
                if (kh == 1) {
#pragma unroll
                    for (int r = 0; r < 4; ++r) {
                        sred[(mq * 2 + 0) * 256 + (lg * 4 + r) * 16 + lrow] = r0[r];
                        sred[(mq * 2 + 1) * 256 + (lg * 4 + r) * 16 + lrow] = r1[r];
                    }
                }
                __syncthreads();
                if (kh == 0) {
                    ushort_t* Hh = PL(parW, 0);
                    ushort_t* Hl = PL(parW, 1);
#pragma unroll
                    for (int nf = 0; nf < 2; ++nf) {
                        int col = nt * 32 + nf * 16 + lrow;
                        float bm = nf ? cB : cA;
#pragma unroll
                        for (int r = 0; r < 4; ++r) {
                            float z = (nf ? r1[r] : r0[r])
                                      + sred[(mq * 2 + nf) * 256 + (lg * 4 + r) * 16 + lrow]
                                      + (nf ? pf1[r] : pf0[r]);
                            float t1 = fmaxf(fabsf(z) + bm, 0.f);
                            float h = copysignf(t1, z);      // modrelu
                            int b = brow + r;
                            ushort_t hi = f2bf(h);
                            ushort_t lo = f2bf(h - bf2f(hi));
                            STS(Hh + b * 1024 + col, hi);
                            STS(Hl + b * 1024 + col, lo);
                            if (p == 511) fst[(size_t)b * 1024 + col] = h;
                        }
                    }
                }
            }
        } else {
            if (p >= 1) {
                const int t = p - 1;
                const ushort_t* Ahp;
                const ushort_t* Alp;
                if (kh == 0) { Ahp = PL(parR, 0) + mrow * 1024 + lk8; Alp = PL(parR, 1) + mrow * 1024 + lk8; }
                else         { Ahp = PL(parW, 2) + mrow * 1024 + lk8; Alp = PL(parW, 3) + mrow * 1024 + lk8; }
                s16x8 A0h[8], A0l[8], A1h[8], A1l[8];
                ISSUE8(A0h, A0l, Ahp, Alp);
                ISSUE8(A1h, A1l, Ahp + 256, Alp + 256);
                f32x4 a0{}, a1{}, a2{};
                WAITB(16, A0h, A0l);              // c0 ready
                L1_CHUNK(A0h, A0l, 0)
                ISSUE8(A0h, A0l, Ahp + 512, Alp + 512);   // c2 -> bank0
                WAITB(16, A1h, A1l);              // c1 ready
                L1_CHUNK(A1h, A1l, 8)
                ISSUE8(A1h, A1l, Ahp + 768, Alp + 768);   // c3 -> bank1
                WAITB(16, A0h, A0l);              // c2 ready
                L1_CHUNK(A0h, A0l, 16)
                WAITB(0, A1h, A1l);               // c3 ready
                L1_CHUNK(A1h, A1l, 24)
                f32x4 rr = a0 + a1 + a2;
                if (kh == 1) {
#pragma unroll
                    for (int r = 0; r < 4; ++r)
                        sred[mq * 256 + (lg * 4 + r) * 16 + lrow] = rr[r];
                }
                __syncthreads();
                if (kh == 0) {
                    int col = nt * 16 + lrow;
                    ushort_t* Hh = PL(parR, 2);
                    ushort_t* Hl = PL(parR, 3);
#pragma unroll
                    for (int r = 0; r < 4; ++r) {
                        float z = rr[r] + sred[mq * 256 + (lg * 4 + r) * 16 + lrow] + cI;
                        float t1 = fmaxf(fabsf(z) + cB, 0.f);
                        float h = copysignf(t1, z);
                        int b = brow + r;
                        ushort_t hi = f2bf(h);
                        ushort_t lo = f2bf(h - bf2f(hi));
                        STS(Hh + b * 1024 + col, hi);
                        STS(Hl + b * 1024 + col, lo);
                        outp[((size_t)b * 512 + t) * 1024 + col] = h;   // plain cached
                        if (t == 511) fst[65536 + (size_t)b * 1024 + col] = h;
                    }
                }
            }
        }
        // ---- fence-free grid barrier ----
        // per-wave: all comm stores (sc0 sc1) completed at the coherence point
        asm volatile("s_waitcnt vmcnt(0)" ::: "memory");
        __syncthreads();
        if (tid == 0) {
            int g = bid >> 5;   // 6 groups of 32
            uint32 lgc = __hip_atomic_fetch_add(&grp[g * 32], 1u, __ATOMIC_RELAXED, __HIP_MEMORY_SCOPE_AGENT);
            if (lgc == (uint32)(p * 32 + 31)) {
                uint32 rc = __hip_atomic_fetch_add(root, 1u, __ATOMIC_RELAXED, __HIP_MEMORY_SCOPE_AGENT);
                if (rc == (uint32)(p * 6 + 5))
                    __hip_atomic_store(flag, (uint32)(p + 1), __ATOMIC_RELAXED, __HIP_MEMORY_SCOPE_AGENT);
            }
            while (__hip_atomic_load(flag, __ATOMIC_RELAXED, __HIP_MEMORY_SCOPE_AGENT) <= (uint32)p)
                __builtin_amdgcn_s_sleep(1);
        }
        __syncthreads();
    }
}

// ---------------------------------------------------------------------------
extern "C" void kernel_launch(void* const* d_in, const int* in_sizes, int n_in,
                              void* d_out, int out_size, void* d_ws, size_t ws_size,
                              hipStream_t stream) {
    const float* x   = (const float*)d_in[0];
    const float* Wi0 = (const float*)d_in[1];
    const float* bi0 = (const float*)d_in[2];
    const float* Wr0 = (const float*)d_in[3];
    const float* bm0 = (const float*)d_in[4];
    const float* Wi1 = (const float*)d_in[5];
    const float* bi1 = (const float*)d_in[6];
    const float* Wr1 = (const float*)d_in[7];
    const float* bm1 = (const float*)d_in[8];
    float* out = (float*)d_out;

    ushort_t* st = (ushort_t*)d_ws;                       // 8 planes * 128 KB = 1 MB
    uint32* bar = (uint32*)((char*)d_ws + (1 << 20));     // barrier state

    // zero the parity-1 state planes (h[-1] = 0) and the barrier counters
    hipMemsetAsync((char*)d_ws + (size_t)4 * 65536 * 2, 0, (size_t)4 * 65536 * 2, stream);
    hipMemsetAsync(bar, 0, 2048, stream);

    hipFuncSetAttribute((const void*)k_rnn, hipFuncAttributeMaxDynamicSharedMemorySize, 135168);

    // K1: input projection for all timesteps, into d_out (doubles as pre0)
    k_pre0<<<2048, 256, 0, stream>>>(x, Wi0, bi0, out);

    // K2: persistent recurrent kernel (192 WGs, 132KB LDS -> 1/CU, co-resident)
    k_rnn<<<192, 256, 135168, stream>>>(Wr0, Wi1, Wr1, bi1, bm0, bm1, out, st, bar);
}

// Round 4
// 5415.626 us; speedup vs baseline: 2.2706x; 1.0338x over previous
//
#include <hip/hip_runtime.h>
#include <stdint.h>

#define BB 64
#define TT 512
#define DD 1024
#define HH 1024

typedef float f32x4 __attribute__((ext_vector_type(4)));
typedef short s16x8 __attribute__((ext_vector_type(8)));
typedef unsigned short ushort_t;
typedef unsigned int uint32;

#define MFMA(a, b, c) __builtin_amdgcn_mfma_f32_16x16x32_bf16((a), (b), (c), 0, 0, 0)

__device__ __forceinline__ ushort_t f2bf(float f) {
    uint32 u = __float_as_uint(f);
    u += 0x7FFFu + ((u >> 16) & 1u);   // RNE
    return (ushort_t)(u >> 16);
}
__device__ __forceinline__ float bf2f(ushort_t h) {
    return __uint_as_float(((uint32)h) << 16);
}
__device__ __forceinline__ void cv8(const float4& v0, const float4& v1, s16x8& hi, s16x8& lo) {
    float a0 = v0.x, a1 = v0.y, a2 = v0.z, a3 = v0.w;
    float a4 = v1.x, a5 = v1.y, a6 = v1.z, a7 = v1.w;
#define SPL(J, V) { ushort_t h = f2bf(V); hi[J] = (short)h; lo[J] = (short)f2bf((V) - bf2f(h)); }
    SPL(0, a0) SPL(1, a1) SPL(2, a2) SPL(3, a3)
    SPL(4, a4) SPL(5, a5) SPL(6, a6) SPL(7, a7)
#undef SPL
}

// ---- coherent (IF$-scope) memory ops: bypass L1/L2, no cache-wide fences ----
#define GLD_(dst, base, OFF) \
    asm volatile("global_load_dwordx4 %0, %1, off offset:" #OFF " sc0 sc1" \
                 : "=v"(dst) : "v"(base) : "memory")
#define GLD(dst, base, OFF) GLD_(dst, base, OFF)

#define ISSUE8(H, L, bh, bl) \
    GLD(H[0], bh, 0);   GLD(H[1], bh, 64);  GLD(H[2], bh, 128); GLD(H[3], bh, 192); \
    GLD(H[4], bh, 256); GLD(H[5], bh, 320); GLD(H[6], bh, 384); GLD(H[7], bh, 448); \
    GLD(L[0], bl, 0);   GLD(L[1], bl, 64);  GLD(L[2], bl, 128); GLD(L[3], bl, 192); \
    GLD(L[4], bl, 256); GLD(L[5], bl, 320); GLD(L[6], bl, 384); GLD(L[7], bl, 448)

#define WAITB_(N, H, L) \
    asm volatile("s_waitcnt vmcnt(" #N ")" \
        : "+v"(H[0]),"+v"(H[1]),"+v"(H[2]),"+v"(H[3]),"+v"(H[4]),"+v"(H[5]),"+v"(H[6]),"+v"(H[7]), \
          "+v"(L[0]),"+v"(L[1]),"+v"(L[2]),"+v"(L[3]),"+v"(L[4]),"+v"(L[5]),"+v"(L[6]),"+v"(L[7]) \
        :: "memory"); \
    __builtin_amdgcn_sched_barrier(0)
#define WAITB(N, H, L) WAITB_(N, H, L)

#define STX(ptr, val) \
    asm volatile("global_store_dwordx4 %0, %1, off sc0 sc1" \
                 :: "v"(ptr), "v"(val) : "memory")

// ---------------------------------------------------------------------------
// K1: pre0[b*T+t][n] = x[b*T+t][:] . Wi0[n][:] + bi0[n]     (3-pass bf16 split)
// Output written into d_out (same layout as out[b][t][n]); overwritten later.
// ---------------------------------------------------------------------------
__global__ __launch_bounds__(256) void k_pre0(
    const float* __restrict__ x, const float* __restrict__ Wi0,
    const float* __restrict__ bi0, float* __restrict__ pre0) {
    __shared__ ushort_t Ah[4096], Al[4096], Bh[4096], Bl[4096];  // 32 KB
    const int bid = blockIdx.x;
    const int mt = bid >> 3, nt = bid & 7;
    const int tid = threadIdx.x;
    const int lane = tid & 63, wave = tid >> 6;
    const int wm = (wave >> 1) * 64, wn = (wave & 1) * 64;
    const int lrow = lane & 15, lg = lane >> 4;

    const float* Ab = x + (size_t)mt * 128 * 1024;
    const float* Bb = Wi0 + (size_t)nt * 128 * 1024;

    f32x4 acc[4][4] = {};

    for (int kt = 0; kt < 32; ++kt) {
        __syncthreads();
#pragma unroll
        for (int g = 0; g < 2; ++g) {
            int gid = g * 256 + tid;
            int row = gid >> 2, kc = gid & 3;
            int loc = ((kc ^ ((row >> 1) & 3)) << 3) + (row << 5);
            const float* sa = Ab + (size_t)row * 1024 + kt * 32 + kc * 8;
            const float* sb = Bb + (size_t)row * 1024 + kt * 32 + kc * 8;
            float4 a0 = *(const float4*)sa, a1 = *(const float4*)(sa + 4);
            float4 b0 = *(const float4*)sb, b1 = *(const float4*)(sb + 4);
            s16x8 vh, vl;
            cv8(a0, a1, vh, vl);
            *(s16x8*)(Ah + loc) = vh; *(s16x8*)(Al + loc) = vl;
            cv8(b0, b1, vh, vl);
            *(s16x8*)(Bh + loc) = vh; *(s16x8*)(Bl + loc) = vl;
        }
        __syncthreads();
        s16x8 fah[4], fal[4], fbh[4], fbl[4];
#pragma unroll
        for (int f = 0; f < 4; ++f) {
            int ra = wm + f * 16 + lrow;
            int la = ((lg ^ ((ra >> 1) & 3)) << 3) + (ra << 5);
            fah[f] = *(const s16x8*)(Ah + la);
            fal[f] = *(const s16x8*)(Al + la);
            int rb = wn + f * 16 + lrow;
            int lb = ((lg ^ ((rb >> 1) & 3)) << 3) + (rb << 5);
            fbh[f] = *(const s16x8*)(Bh + lb);
            fbl[f] = *(const s16x8*)(Bl + lb);
        }
#pragma unroll
        for (int mf = 0; mf < 4; ++mf)
#pragma unroll
            for (int nf = 0; nf < 4; ++nf)
                acc[mf][nf] = MFMA(fah[mf], fbh[nf], acc[mf][nf]);
#pragma unroll
        for (int mf = 0; mf < 4; ++mf)
#pragma unroll
            for (int nf = 0; nf < 4; ++nf)
                acc[mf][nf] = MFMA(fah[mf], fbl[nf], acc[mf][nf]);
#pragma unroll
        for (int mf = 0; mf < 4; ++mf)
#pragma unroll
            for (int nf = 0; nf < 4; ++nf)
                acc[mf][nf] = MFMA(fal[mf], fbh[nf], acc[mf][nf]);
    }
#pragma unroll
    for (int nf = 0; nf < 4; ++nf) {
        int col = nt * 128 + wn + nf * 16 + lrow;
        float bc = bi0[col];
#pragma unroll
        for (int mf = 0; mf < 4; ++mf)
#pragma unroll
            for (int r = 0; r < 4; ++r) {
                int row = mt * 128 + wm + mf * 16 + lg * 4 + r;
                pre0[(size_t)row * 1024 + col] = acc[mf][nf][r] + bc;
            }
    }
}

// ---------------------------------------------------------------------------
// K2: persistent 2-layer RNN. 192 WGs (64 L0 + 128 L1), 513 phases.
// State planes in ws (ushort): [parity(2)][h0hi,h0lo,h1hi,h1lo][64][1024]
// Communication via sc0/sc1 (IF$-coherent) ops.
// Barrier: RMW-free per-WG epoch flags (128B apart), direct all-flag poll,
// two independent domains split by batch-half (mh).
// ---------------------------------------------------------------------------
#define PL(par, which) (st + (size_t)((((par) << 2) + (which))) * 65536)
#define FLG(i) (bar + (size_t)(i) * 32)

#define L0_CHUNK(H, L, KB) \
_Pragma("unroll") \
    for (int i = 0; i < 8; ++i) { \
        int gkb = kh * 64 + ((KB) + i) * 4 + lg; \
        int l0 = ((gkb ^ (lrow & 7)) << 3) + (lrow << 10); \
        int l1b = ((gkb ^ (lrow & 7)) << 3) + ((16 + lrow) << 10); \
        s16x8 b0h = *(const s16x8*)(Bh + l0), b0l = *(const s16x8*)(Bl + l0); \
        s16x8 b1h = *(const s16x8*)(Bh + l1b), b1l = *(const s16x8*)(Bl + l1b); \
        a00 = MFMA(H[i], b0h, a00); a10 = MFMA(H[i], b1h, a10); \
        a01 = MFMA(H[i], b0l, a01); a11 = MFMA(H[i], b1l, a11); \
        a02 = MFMA(L[i], b0h, a02); a12 = MFMA(L[i], b1h, a12); \
    }

#define L1_CHUNK(H, L, KB) \
_Pragma("unroll") \
    for (int i = 0; i < 8; ++i) { \
        int gkb = kh * 128 + ((KB) + i) * 4 + lg; \
        int loc = ((gkb ^ (lrow & 7)) << 3) + (lrow << 11); \
        s16x8 bh = *(const s16x8*)(Bh + loc), bl = *(const s16x8*)(Bl + loc); \
        a0 = MFMA(H[i], bh, a0); \
        a1 = MFMA(H[i], bl, a1); \
        a2 = MFMA(L[i], bh, a2); \
    }

__global__ __launch_bounds__(256, 1) void k_rnn(
    const float* __restrict__ Wr0, const float* __restrict__ Wi1,
    const float* __restrict__ Wr1, const float* __restrict__ bi1,
    const float* __restrict__ bm0, const float* __restrict__ bm1,
    float* __restrict__ dout, ushort_t* __restrict__ st, uint32* __restrict__ bar) {
    extern __shared__ __align__(16) char smem[];
    ushort_t* Bh = (ushort_t*)smem;          // 64 KB hi weights
    ushort_t* Bl = Bh + 32768;               // 64 KB lo weights
    float* sred = (float*)(smem + 131072);   // 4 KB k-half reduce scratch
    ushort_t* stage = (ushort_t*)(smem + 135168);  // 4 KB output staging

    const int bid = blockIdx.x;
    const bool isL0 = bid < 64;
    const int tid = threadIdx.x, lane = tid & 63, wave = tid >> 6;
    const int mq = wave >> 1, kh = wave & 1;
    const int lrow = lane & 15, lg = lane >> 4, lk8 = lg << 3;
    int mh, nt;
    if (isL0) { mh = bid & 1; nt = bid >> 1; }
    else      { int id = bid - 64; mh = id & 1; nt = id >> 1; }

    // ---- stage constant weights into LDS (hi/lo bf16, XOR-swizzled) ----
    if (isL0) {
        const float* W = Wr0 + (size_t)nt * 32 * 1024;
        for (int i = 0; i < 16; ++i) {
            int gid = i * 256 + tid;
            int row = gid >> 7, gk = gid & 127;
            const float* src = W + (size_t)row * 1024 + gk * 8;
            float4 v0 = *(const float4*)src, v1 = *(const float4*)(src + 4);
            s16x8 vh, vl;
            cv8(v0, v1, vh, vl);
            int loc = ((gk ^ (row & 7)) << 3) + (row << 10);
            *(s16x8*)(Bh + loc) = vh; *(s16x8*)(Bl + loc) = vl;
        }
    } else {
        for (int i = 0; i < 16; ++i) {
            int gid = i * 256 + tid;
            int row = gid >> 8, gk = gid & 255;
            const float* src = (gk < 128)
                ? Wi1 + (size_t)(nt * 16 + row) * 1024 + gk * 8
                : Wr1 + (size_t)(nt * 16 + row) * 1024 + (gk - 128) * 8;
            float4 v0 = *(const float4*)src, v1 = *(const float4*)(src + 4);
            s16x8 vh, vl;
            cv8(v0, v1, vh, vl);
            int loc = ((gk ^ (row & 7)) << 3) + (row << 11);
            *(s16x8*)(Bh + loc) = vh; *(s16x8*)(Bl + loc) = vl;
        }
    }
    __syncthreads();

    float cA = 0.f, cB = 0.f, cI = 0.f;
    if (kh == 0) {
        if (isL0) { cA = bm0[nt * 32 + lrow]; cB = bm0[nt * 32 + 16 + lrow]; }
        else      { int col = nt * 16 + lrow; cI = bi1[col]; cB = bm1[col]; }
    }

    float* outp = dout;
    const float* pre0 = dout;
    float* fst = dout + (size_t)BB * TT * HH;

    const int mrow = mh * 32 + mq * 16 + lrow;
    const int brow = mh * 32 + mq * 16 + lg * 4;

    // pre0 prefetch registers (L0, kh==0 waves) — loaded for p=0 up front
    float pf0[4], pf1[4];
    if (isL0 && kh == 0) {
#pragma unroll
        for (int r = 0; r < 4; ++r) {
            pf0[r] = pre0[((size_t)(brow + r) * 512) * 1024 + nt * 32 + lrow];
            pf1[r] = pre0[((size_t)(brow + r) * 512) * 1024 + nt * 32 + 16 + lrow];
        }
    }

#pragma unroll 1
    for (int p = 0; p <= 512; ++p) {
        const int parW = p & 1, parR = parW ^ 1;
        if (isL0) {
            if (p <= 511) {
                const ushort_t* Ahp = PL(parR, 0) + mrow * 1024 + kh * 512 + lk8;
                const ushort_t* Alp = PL(parR, 1) + mrow * 1024 + kh * 512 + lk8;
                s16x8 A0h[8], A0l[8], A1h[8], A1l[8];
                ISSUE8(A0h, A0l, Ahp, Alp);
                ISSUE8(A1h, A1l, Ahp + 256, Alp + 256);
                f32x4 a00{}, a01{}, a02{}, a10{}, a11{}, a12{};
                WAITB(16, A0h, A0l);       // chunk0 (+ any older pf) done
                L0_CHUNK(A0h, A0l, 0)
                WAITB(0, A1h, A1l);        // chunk1 done
                L0_CHUNK(A1h, A1l, 8)
                f32x4 r0 = a00 + a01 + a02, r1 = a10 + a11 + a12;
                if (kh == 1) {
#pragma unroll
                    for (int r = 0; r < 4; ++r) {
                        sred[(mq * 2 + 0) * 256 + (lg * 4 + r) * 16 + lrow] = r0[r];
                        sred[(mq * 2 + 1) * 256 + (lg * 4 + r) * 16 + lrow] = r1[r];
                    }
                }
                __syncthreads();
                if (kh == 0) {
                    ushort_t* stH = stage;            // [32][32]
                    ushort_t* stL = stage + 1024;
#pragma unroll
                    for (int nf = 0; nf < 2; ++nf) {
                        int colL = nf * 16 + lrow;
                        float bm = nf ? cB : cA;
#pragma unroll
                        for (int r = 0; r < 4; ++r) {
                            float z = (nf ? r1[r] : r0[r])
                                      + sred[(mq * 2 + nf) * 256 + (lg * 4 + r) * 16 + lrow]
                                      + (nf ? pf1[r] : pf0[r]);
                            float t1 = fmaxf(fabsf(z) + bm, 0.f);
                            float h = copysignf(t1, z);      // modrelu
                            int bl = mq * 16 + lg * 4 + r;
                            ushort_t hi = f2bf(h);
                            stH[bl * 32 + colL] = hi;
                            stL[bl * 32 + colL] = f2bf(h - bf2f(hi));
                            if (p == 511) fst[(size_t)(mh * 32 + bl) * 1024 + nt * 32 + colL] = h;
                        }
                    }
                }
                __syncthreads();
                {   // one 16B coherent store per thread: 32 rows x 32 cols x {hi,lo}
                    int plane = tid >> 7, rem = tid & 127;
                    int row = rem >> 2, q = rem & 3;
                    s16x8 v = *(const s16x8*)(stage + plane * 1024 + rem * 8);
                    ushort_t* gp = PL(parW, plane) + (mh * 32 + row) * 1024 + nt * 32 + q * 8;
                    STX(gp, v);
                }
            }
        } else {
            if (p >= 1) {
                const int t = p - 1;
                const ushort_t* Ahp;
                const ushort_t* Alp;
                if (kh == 0) { Ahp = PL(parR, 0) + mrow * 1024 + lk8; Alp = PL(parR, 1) + mrow * 1024 + lk8; }
                else         { Ahp = PL(parW, 2) + mrow * 1024 + lk8; Alp = PL(parW, 3) + mrow * 1024 + lk8; }
                s16x8 A0h[8], A0l[8], A1h[8], A1l[8];
                ISSUE8(A0h, A0l, Ahp, Alp);
                ISSUE8(A1h, A1l, Ahp + 256, Alp + 256);
                f32x4 a0{}, a1{}, a2{};
                WAITB(16, A0h, A0l);              // c0 ready
                L1_CHUNK(A0h, A0l, 0)
                ISSUE8(A0h, A0l, Ahp + 512, Alp + 512);   // c2 -> bank0
                WAITB(16, A1h, A1l);              // c1 ready
                L1_CHUNK(A1h, A1l, 8)
                ISSUE8(A1h, A1l, Ahp + 768, Alp + 768);   // c3 -> bank1
                WAITB(16, A0h, A0l);              // c2 ready
                L1_CHUNK(A0h, A0l, 16)
                WAITB(0, A1h, A1l);               // c3 ready
                L1_CHUNK(A1h, A1l, 24)
                f32x4 rr = a0 + a1 + a2;
                if (kh == 1) {
#pragma unroll
                    for (int r = 0; r < 4; ++r)
                        sred[mq * 256 + (lg * 4 + r) * 16 + lrow] = rr[r];
                }
                __syncthreads();
                if (kh == 0) {
                    ushort_t* stH = stage;               // [32][16]
                    ushort_t* stL = stage + 512;
                    float* stO = (float*)(stage + 1024); // [32][16] f32
#pragma unroll
                    for (int r = 0; r < 4; ++r) {
                        float z = rr[r] + sred[mq * 256 + (lg * 4 + r) * 16 + lrow] + cI;
                        float t1 = fmaxf(fabsf(z) + cB, 0.f);
                        float h = copysignf(t1, z);
                        int bl = mq * 16 + lg * 4 + r;
                        ushort_t hi = f2bf(h);
                        stH[bl * 16 + lrow] = hi;
                        stL[bl * 16 + lrow] = f2bf(h - bf2f(hi));
                        stO[bl * 16 + lrow] = h;
                        if (t == 511) fst[65536 + (size_t)(mh * 32 + bl) * 1024 + nt * 16 + lrow] = h;
                    }
                }
                __syncthreads();
                if (tid < 128) {   // state: 32 rows x 16 cols x {hi,lo}, 16B each
                    int plane = (tid >> 6) & 1, rem = tid & 63;
                    int row = rem >> 1, q = rem & 1;
                    s16x8 v = *(const s16x8*)(stage + plane * 512 + rem * 8);
                    ushort_t* gp = PL(parR, 2 + plane) + (mh * 32 + row) * 1024 + nt * 16 + q * 8;
                    STX(gp, v);
                } else {           // out tile: 32 rows x 16 f32, coalesced float4
                    int rem = tid - 128;
                    int row = rem >> 2, q = rem & 3;
                    float4 v = *(const float4*)((const float*)(stage + 1024) + rem * 4);
                    *(float4*)(outp + ((size_t)(mh * 32 + row) * 512 + t) * 1024 + nt * 16 + q * 4) = v;
                }
            }
        }
        // ---- RMW-free grid barrier, per-mh domain ----
        asm volatile("s_waitcnt vmcnt(0)" ::: "memory");   // all stores at coherence point
        __syncthreads();
        // pre0 prefetch for next phase rides under the barrier wait
        if (isL0 && kh == 0 && p < 511) {
#pragma unroll
            for (int r = 0; r < 4; ++r) {
                pf0[r] = pre0[((size_t)(brow + r) * 512 + (p + 1)) * 1024 + nt * 32 + lrow];
                pf1[r] = pre0[((size_t)(brow + r) * 512 + (p + 1)) * 1024 + nt * 32 + 16 + lrow];
            }
        }
        if (tid == 0)
            __hip_atomic_store(FLG(bid), (uint32)(p + 1), __ATOMIC_RELAXED, __HIP_MEMORY_SCOPE_AGENT);
        if (wave == 0) {
            const uint32 e = (uint32)(p + 1);
            const int l0i = 2 * lane + mh;        // lanes 0..31 -> 32 L0 flags
            const int l1i = 64 + 2 * lane + mh;   // lanes 0..63 -> 64 L1 flags
            for (;;) {
                uint32 f1 = __hip_atomic_load(FLG(l1i), __ATOMIC_RELAXED, __HIP_MEMORY_SCOPE_AGENT);
                uint32 f0 = (lane < 32)
                    ? __hip_atomic_load(FLG(l0i), __ATOMIC_RELAXED, __HIP_MEMORY_SCOPE_AGENT) : e;
                if (__all((f1 >= e) && (f0 >= e))) break;
                __builtin_amdgcn_s_sleep(1);
            }
        }
        __syncthreads();
    }
}

// ---------------------------------------------------------------------------
extern "C" void kernel_launch(void* const* d_in, const int* in_sizes, int n_in,
                              void* d_out, int out_size, void* d_ws, size_t ws_size,
                              hipStream_t stream) {
    const float* x   = (const float*)d_in[0];
    const float* Wi0 = (const float*)d_in[1];
    const float* bi0 = (const float*)d_in[2];
    const float* Wr0 = (const float*)d_in[3];
    const float* bm0 = (const float*)d_in[4];
    const float* Wi1 = (const float*)d_in[5];
    const float* bi1 = (const float*)d_in[6];
    const float* Wr1 = (const float*)d_in[7];
    const float* bm1 = (const float*)d_in[8];
    float* out = (float*)d_out;

    ushort_t* st = (ushort_t*)d_ws;                       // 8 planes * 128 KB = 1 MB
    uint32* bar = (uint32*)((char*)d_ws + (1 << 20));     // per-WG flags, 128B stride

    // zero the parity-1 state planes (h[-1] = 0) and the flags
    hipMemsetAsync((char*)d_ws + (size_t)4 * 65536 * 2, 0, (size_t)4 * 65536 * 2, stream);
    hipMemsetAsync(bar, 0, 32768, stream);

    hipFuncSetAttribute((const void*)k_rnn, hipFuncAttributeMaxDynamicSharedMemorySize, 139264);

    // K1: input projection for all timesteps, into d_out (doubles as pre0)
    k_pre0<<<2048, 256, 0, stream>>>(x, Wi0, bi0, out);

    // K2: persistent recurrent kernel (192 WGs, 136KB LDS -> 1/CU, co-resident)
    k_rnn<<<192, 256, 139264, stream>>>(Wr0, Wi1, Wr1, bi1, bm0, bm1, out, st, bar);
}

// Round 5
// 4320.352 us; speedup vs baseline: 2.8462x; 1.2535x over previous
//
#include <hip/hip_runtime.h>
#include <stdint.h>

#define BB 64
#define TT 512
#define DD 1024
#define HH 1024

typedef float f32x4 __attribute__((ext_vector_type(4)));
typedef short s16x8 __attribute__((ext_vector_type(8)));
typedef unsigned short ushort_t;
typedef unsigned int uint32;

#define MFMA(a, b, c) __builtin_amdgcn_mfma_f32_16x16x32_bf16((a), (b), (c), 0, 0, 0)

__device__ __forceinline__ ushort_t f2bf(float f) {
    uint32 u = __float_as_uint(f);
    u += 0x7FFFu + ((u >> 16) & 1u);   // RNE
    return (ushort_t)(u >> 16);
}
__device__ __forceinline__ float bf2f(ushort_t h) {
    return __uint_as_float(((uint32)h) << 16);
}
__device__ __forceinline__ void cv8(const float4& v0, const float4& v1, s16x8& hi, s16x8& lo) {
    float a0 = v0.x, a1 = v0.y, a2 = v0.z, a3 = v0.w;
    float a4 = v1.x, a5 = v1.y, a6 = v1.z, a7 = v1.w;
#define SPL(J, V) { ushort_t h = f2bf(V); hi[J] = (short)h; lo[J] = (short)f2bf((V) - bf2f(h)); }
    SPL(0, a0) SPL(1, a1) SPL(2, a2) SPL(3, a3)
    SPL(4, a4) SPL(5, a5) SPL(6, a6) SPL(7, a7)
#undef SPL
}

// ---- coherent (IF$-scope) memory ops: bypass L1/L2, no cache-wide fences ----
#define GLD_(dst, base, OFF) \
    asm volatile("global_load_dwordx4 %0, %1, off offset:" #OFF " sc0 sc1" \
                 : "=v"(dst) : "v"(base) : "memory")
#define GLD(dst, base, OFF) GLD_(dst, base, OFF)

#define ISSUE8(H, L, bh, bl) \
    GLD(H[0], bh, 0);   GLD(H[1], bh, 64);  GLD(H[2], bh, 128); GLD(H[3], bh, 192); \
    GLD(H[4], bh, 256); GLD(H[5], bh, 320); GLD(H[6], bh, 384); GLD(H[7], bh, 448); \
    GLD(L[0], bl, 0);   GLD(L[1], bl, 64);  GLD(L[2], bl, 128); GLD(L[3], bl, 192); \
    GLD(L[4], bl, 256); GLD(L[5], bl, 320); GLD(L[6], bl, 384); GLD(L[7], bl, 448)

#define WAITB_(N, H, L) \
    asm volatile("s_waitcnt vmcnt(" #N ")" \
        : "+v"(H[0]),"+v"(H[1]),"+v"(H[2]),"+v"(H[3]),"+v"(H[4]),"+v"(H[5]),"+v"(H[6]),"+v"(H[7]), \
          "+v"(L[0]),"+v"(L[1]),"+v"(L[2]),"+v"(L[3]),"+v"(L[4]),"+v"(L[5]),"+v"(L[6]),"+v"(L[7]) \
        :: "memory"); \
    __builtin_amdgcn_sched_barrier(0)
#define WAITB(N, H, L) WAITB_(N, H, L)

#define STX(ptr, val) \
    asm volatile("global_store_dwordx4 %0, %1, off sc0 sc1" \
                 :: "v"(ptr), "v"(val) : "memory")

// ---------------------------------------------------------------------------
// K1: pre0[b*T+t][n] = x[b*T+t][:] . Wi0[n][:] + bi0[n]     (3-pass bf16 split)
// Output written into d_out (same layout as out[b][t][n]); overwritten later.
// ---------------------------------------------------------------------------
__global__ __launch_bounds__(256) void k_pre0(
    const float* __restrict__ x, const float* __restrict__ Wi0,
    const float* __restrict__ bi0, float* __restrict__ pre0) {
    __shared__ ushort_t Ah[4096], Al[4096], Bh[4096], Bl[4096];  // 32 KB
    const int bid = blockIdx.x;
    const int mt = bid >> 3, nt = bid & 7;
    const int tid = threadIdx.x;
    const int lane = tid & 63, wave = tid >> 6;
    const int wm = (wave >> 1) * 64, wn = (wave & 1) * 64;
    const int lrow = lane & 15, lg = lane >> 4;

    const float* Ab = x + (size_t)mt * 128 * 1024;
    const float* Bb = Wi0 + (size_t)nt * 128 * 1024;

    f32x4 acc[4][4] = {};

    for (int kt = 0; kt < 32; ++kt) {
        __syncthreads();
#pragma unroll
        for (int g = 0; g < 2; ++g) {
            int gid = g * 256 + tid;
            int row = gid >> 2, kc = gid & 3;
            int loc = ((kc ^ ((row >> 1) & 3)) << 3) + (row << 5);
            const float* sa = Ab + (size_t)row * 1024 + kt * 32 + kc * 8;
            const float* sb = Bb + (size_t)row * 1024 + kt * 32 + kc * 8;
            float4 a0 = *(const float4*)sa, a1 = *(const float4*)(sa + 4);
            float4 b0 = *(const float4*)sb, b1 = *(const float4*)(sb + 4);
            s16x8 vh, vl;
            cv8(a0, a1, vh, vl);
            *(s16x8*)(Ah + loc) = vh; *(s16x8*)(Al + loc) = vl;
            cv8(b0, b1, vh, vl);
            *(s16x8*)(Bh + loc) = vh; *(s16x8*)(Bl + loc) = vl;
        }
        __syncthreads();
        s16x8 fah[4], fal[4], fbh[4], fbl[4];
#pragma unroll
        for (int f = 0; f < 4; ++f) {
            int ra = wm + f * 16 + lrow;
            int la = ((lg ^ ((ra >> 1) & 3)) << 3) + (ra << 5);
            fah[f] = *(const s16x8*)(Ah + la);
            fal[f] = *(const s16x8*)(Al + la);
            int rb = wn + f * 16 + lrow;
            int lb = ((lg ^ ((rb >> 1) & 3)) << 3) + (rb << 5);
            fbh[f] = *(const s16x8*)(Bh + lb);
            fbl[f] = *(const s16x8*)(Bl + lb);
        }
#pragma unroll
        for (int mf = 0; mf < 4; ++mf)
#pragma unroll
            for (int nf = 0; nf < 4; ++nf)
                acc[mf][nf] = MFMA(fah[mf], fbh[nf], acc[mf][nf]);
#pragma unroll
        for (int mf = 0; mf < 4; ++mf)
#pragma unroll
            for (int nf = 0; nf < 4; ++nf)
                acc[mf][nf] = MFMA(fah[mf], fbl[nf], acc[mf][nf]);
#pragma unroll
        for (int mf = 0; mf < 4; ++mf)
#pragma unroll
            for (int nf = 0; nf < 4; ++nf)
                acc[mf][nf] = MFMA(fal[mf], fbh[nf], acc[mf][nf]);
    }
#pragma unroll
    for (int nf = 0; nf < 4; ++nf) {
        int col = nt * 128 + wn + nf * 16 + lrow;
        float bc = bi0[col];
#pragma unroll
        for (int mf = 0; mf < 4; ++mf)
#pragma unroll
            for (int r = 0; r < 4; ++r) {
                int row = mt * 128 + wm + mf * 16 + lg * 4 + r;
                pre0[(size_t)row * 1024 + col] = acc[mf][nf][r] + bc;
            }
    }
}

// ---------------------------------------------------------------------------
// K2: persistent 2-layer RNN, 3-role pipeline. 192 WGs, 514 phases.
//   role0 (bid 0..63):    h0[p]   = modrelu(pre0[p] + Wr0.h0[p-1], bm0)
//   role1 (bid 64..127):  q[p-1]  = Wi1.h0[p-1] + bi1
//   role2 (bid 128..191): h1[p-2] = modrelu(q[p-2] + Wr1.h1[p-3], bm1)
// Every WG: N=32 cols, K=1024 -> 128 KB coherent A-stream per phase (balanced).
// State planes in ws (ushort): [parity(2)][h0hi,h0lo,h1hi,h1lo][64][1024]
// q in ws (f32): [parity(2)][64][1024]. sc0/sc1 comm, RMW-free flag barrier.
// ---------------------------------------------------------------------------
#define PL(par, which) (st + (size_t)((((par) << 2) + (which))) * 65536)
#define FLG(i) (bar + (size_t)(i) * 32)

#define ROLE_CHUNK(H, L, KB) \
_Pragma("unroll") \
    for (int i = 0; i < 8; ++i) { \
        int gkb = kh * 64 + ((KB) + i) * 4 + lg; \
        int l0 = ((gkb ^ (lrow & 7)) << 3) + (lrow << 10); \
        int l1b = ((gkb ^ (lrow & 7)) << 3) + ((16 + lrow) << 10); \
        s16x8 b0h = *(const s16x8*)(Bh + l0), b0l = *(const s16x8*)(Bl + l0); \
        s16x8 b1h = *(const s16x8*)(Bh + l1b), b1l = *(const s16x8*)(Bl + l1b); \
        a00 = MFMA(H[i], b0h, a00); a10 = MFMA(H[i], b1h, a10); \
        a01 = MFMA(H[i], b0l, a01); a11 = MFMA(H[i], b1l, a11); \
        a02 = MFMA(L[i], b0h, a02); a12 = MFMA(L[i], b1h, a12); \
    }

__global__ __launch_bounds__(256, 1) void k_rnn(
    const float* __restrict__ Wr0, const float* __restrict__ Wi1,
    const float* __restrict__ Wr1, const float* __restrict__ bi1,
    const float* __restrict__ bm0, const float* __restrict__ bm1,
    float* __restrict__ dout, ushort_t* __restrict__ st,
    float* __restrict__ qb, uint32* __restrict__ bar) {
    extern __shared__ __align__(16) char smem[];
    ushort_t* Bh = (ushort_t*)smem;                 // 64 KB hi weights
    ushort_t* Bl = Bh + 32768;                      // 64 KB lo weights
    float* sred = (float*)(smem + 131072);          // 4 KB k-half reduce
    ushort_t* stH = (ushort_t*)(smem + 135168);     // 2 KB
    ushort_t* stL = stH + 1024;                     // 2 KB
    float* stO = (float*)(smem + 139264);           // 4 KB f32 staging
    float* qs  = (float*)(smem + 143360);           // 4 KB q tile

    const int bid = blockIdx.x;
    const int role = bid >> 6;                      // 0,1,2
    const int sub = bid & 63;
    const int mh = sub & 1, nt = sub >> 1;          // nt: 0..31 (32-col tiles)
    const int tid = threadIdx.x, lane = tid & 63, wave = tid >> 6;
    const int mq = wave >> 1, kh = wave & 1;
    const int lrow = lane & 15, lg = lane >> 4, lk8 = lg << 3;

    // ---- stage this role's weight tile (N=32 x K=1024, hi/lo, swizzled) ----
    {
        const float* W = (role == 0 ? Wr0 : role == 1 ? Wi1 : Wr1) + (size_t)nt * 32 * 1024;
        for (int i = 0; i < 16; ++i) {
            int gid = i * 256 + tid;               // 4096 granules: [32 rows][128 gk]
            int row = gid >> 7, gk = gid & 127;
            const float* src = W + (size_t)row * 1024 + gk * 8;
            float4 v0 = *(const float4*)src, v1 = *(const float4*)(src + 4);
            s16x8 vh, vl;
            cv8(v0, v1, vh, vl);
            int loc = ((gk ^ (row & 7)) << 3) + (row << 10);
            *(s16x8*)(Bh + loc) = vh; *(s16x8*)(Bl + loc) = vl;
        }
    }
    __syncthreads();

    // per-lane epilogue constants (kh==0 lanes finalize)
    float c0 = 0.f, c1 = 0.f;
    if (kh == 0) {
        const float* cb = role == 0 ? bm0 : role == 1 ? bi1 : bm1;
        c0 = cb[nt * 32 + lrow];
        c1 = cb[nt * 32 + 16 + lrow];
    }

    float* outp = dout;
    const float* pre0 = dout;
    float* fst = dout + (size_t)BB * TT * HH;

    const int mrow = mh * 32 + mq * 16 + lrow;
    const int brow = mh * 32 + mq * 16 + lg * 4;

    // pre0 prefetch (role0, kh==0) for p=0
    float pf0[4], pf1[4];
    if (role == 0 && kh == 0) {
#pragma unroll
        for (int r = 0; r < 4; ++r) {
            pf0[r] = pre0[((size_t)(brow + r) * 512) * 1024 + nt * 32 + lrow];
            pf1[r] = pre0[((size_t)(brow + r) * 512) * 1024 + nt * 32 + 16 + lrow];
        }
    }

#pragma unroll 1
    for (int p = 0; p <= 513; ++p) {
        const int parW = p & 1, parR = parW ^ 1;
        const bool act = (role == 0) ? (p <= 511)
                       : (role == 1) ? (p >= 1 && p <= 512)
                                     : (p >= 2);
        if (act) {
            const ushort_t* Ahp = (role == 2 ? PL(parR, 2) : PL(parR, 0)) + mrow * 1024 + kh * 512 + lk8;
            const ushort_t* Alp = (role == 2 ? PL(parR, 3) : PL(parR, 1)) + mrow * 1024 + kh * 512 + lk8;
            f32x4 qv{};
            if (role == 2) {       // q tile load first (oldest in vm queue)
                const float* qpt = qb + (size_t)parW * 65536
                                   + (mh * 32 + (tid >> 3)) * 1024 + nt * 32 + (tid & 7) * 4;
                GLD(qv, qpt, 0);
            }
            s16x8 A0h[8], A0l[8], A1h[8], A1l[8];
            ISSUE8(A0h, A0l, Ahp, Alp);
            ISSUE8(A1h, A1l, Ahp + 256, Alp + 256);
            f32x4 a00{}, a01{}, a02{}, a10{}, a11{}, a12{};
            WAITB(16, A0h, A0l);       // chunk0 (and q, oldest) complete
            if (role == 2)
                *(f32x4*)(qs + (tid >> 3) * 32 + (tid & 7) * 4) = qv;
            ROLE_CHUNK(A0h, A0l, 0)
            WAITB(0, A1h, A1l);        // chunk1 complete
            ROLE_CHUNK(A1h, A1l, 8)
            f32x4 r0 = a00 + a01 + a02, r1 = a10 + a11 + a12;
            if (kh == 1) {
#pragma unroll
                for (int r = 0; r < 4; ++r) {
                    sred[(mq * 2 + 0) * 256 + (lg * 4 + r) * 16 + lrow] = r0[r];
                    sred[(mq * 2 + 1) * 256 + (lg * 4 + r) * 16 + lrow] = r1[r];
                }
            }
            __syncthreads();
            if (kh == 0) {
#pragma unroll
                for (int nf = 0; nf < 2; ++nf) {
                    int colL = nf * 16 + lrow;
                    float cc = nf ? c1 : c0;
#pragma unroll
                    for (int r = 0; r < 4; ++r) {
                        float s = (nf ? r1[r] : r0[r])
                                  + sred[(mq * 2 + nf) * 256 + (lg * 4 + r) * 16 + lrow];
                        int bl = mq * 16 + lg * 4 + r;
                        if (role == 0) {
                            float z = s + (nf ? pf1[r] : pf0[r]);
                            float h = copysignf(fmaxf(fabsf(z) + cc, 0.f), z);
                            ushort_t hi = f2bf(h);
                            stH[bl * 32 + colL] = hi;
                            stL[bl * 32 + colL] = f2bf(h - bf2f(hi));
                            if (p == 511) fst[(size_t)(mh * 32 + bl) * 1024 + nt * 32 + colL] = h;
                        } else if (role == 1) {
                            stO[bl * 32 + colL] = s + cc;     // q = Wi1.h0 + bi1
                        } else {
                            float z = s + qs[bl * 32 + colL];
                            float h = copysignf(fmaxf(fabsf(z) + cc, 0.f), z);
                            ushort_t hi = f2bf(h);
                            stH[bl * 32 + colL] = hi;
                            stL[bl * 32 + colL] = f2bf(h - bf2f(hi));
                            stO[bl * 32 + colL] = h;
                        }
                    }
                }
            }
            __syncthreads();
            // ---- packed store-out (one 16B op per thread per target) ----
            if (role == 0) {
                int plane = tid >> 7, rem = tid & 127;
                int row = rem >> 2, q4 = rem & 3;
                s16x8 v = *(const s16x8*)((plane ? stL : stH) + rem * 8);
                ushort_t* gp = PL(parW, plane) + (mh * 32 + row) * 1024 + nt * 32 + q4 * 8;
                STX(gp, v);
            } else if (role == 1) {
                int row = tid >> 3, c4 = (tid & 7) * 4;
                f32x4 v = *(const f32x4*)(stO + row * 32 + c4);
                float* gp = qb + (size_t)parR * 65536 + (mh * 32 + row) * 1024 + nt * 32 + c4;
                STX(gp, v);
            } else {
                const int t = p - 2;
                {   // h1 state hi/lo
                    int plane = tid >> 7, rem = tid & 127;
                    int row = rem >> 2, q4 = rem & 3;
                    s16x8 v = *(const s16x8*)((plane ? stL : stH) + rem * 8);
                    ushort_t* gp = PL(parW, 2 + plane) + (mh * 32 + row) * 1024 + nt * 32 + q4 * 8;
                    STX(gp, v);
                }
                {   // out tile (plain cached float4) + final state
                    int row = tid >> 3, c4 = (tid & 7) * 4;
                    float4 v = *(const float4*)(stO + row * 32 + c4);
                    *(float4*)(outp + ((size_t)(mh * 32 + row) * 512 + t) * 1024 + nt * 32 + c4) = v;
                    if (t == 511)
                        *(float4*)(fst + 65536 + (size_t)(mh * 32 + row) * 1024 + nt * 32 + c4) = v;
                }
            }
        }
        // ---- RMW-free grid barrier, per-mh domain (96 WGs each) ----
        asm volatile("s_waitcnt vmcnt(0)" ::: "memory");   // all stores at coherence point
        __syncthreads();
        if (role == 0 && kh == 0 && p < 511) {   // pre0 prefetch rides under the poll
#pragma unroll
            for (int r = 0; r < 4; ++r) {
                pf0[r] = pre0[((size_t)(brow + r) * 512 + (p + 1)) * 1024 + nt * 32 + lrow];
                pf1[r] = pre0[((size_t)(brow + r) * 512 + (p + 1)) * 1024 + nt * 32 + 16 + lrow];
            }
        }
        if (tid == 0)
            __hip_atomic_store(FLG(bid), (uint32)(p + 1), __ATOMIC_RELAXED, __HIP_MEMORY_SCOPE_AGENT);
        if (wave == 0) {
            const uint32 e = (uint32)(p + 1);
            const int fa = 2 * lane + mh;               // flags 0..127
            const int fb = 128 + 2 * (lane & 31) + mh;  // flags 128..191
            for (;;) {
                uint32 v1 = __hip_atomic_load(FLG(fa), __ATOMIC_RELAXED, __HIP_MEMORY_SCOPE_AGENT);
                uint32 v2 = (lane < 32)
                    ? __hip_atomic_load(FLG(fb), __ATOMIC_RELAXED, __HIP_MEMORY_SCOPE_AGENT) : e;
                if (__all((v1 >= e) && (v2 >= e))) break;
                __builtin_amdgcn_s_sleep(1);
            }
        }
        __syncthreads();
    }
}

// ---------------------------------------------------------------------------
extern "C" void kernel_launch(void* const* d_in, const int* in_sizes, int n_in,
                              void* d_out, int out_size, void* d_ws, size_t ws_size,
                              hipStream_t stream) {
    const float* x   = (const float*)d_in[0];
    const float* Wi0 = (const float*)d_in[1];
    const float* bi0 = (const float*)d_in[2];
    const float* Wr0 = (const float*)d_in[3];
    const float* bm0 = (const float*)d_in[4];
    const float* Wi1 = (const float*)d_in[5];
    const float* bi1 = (const float*)d_in[6];
    const float* Wr1 = (const float*)d_in[7];
    const float* bm1 = (const float*)d_in[8];
    float* out = (float*)d_out;

    ushort_t* st = (ushort_t*)d_ws;                            // 8 planes * 128 KB = 1 MB
    float* qb = (float*)((char*)d_ws + (1 << 20));             // q: 2 * 256 KB
    uint32* bar = (uint32*)((char*)d_ws + (1 << 20) + 524288); // per-WG flags, 128B stride

    // zero the parity-1 state planes (h0[-1]=h1[-1]=0) and the flags
    hipMemsetAsync((char*)d_ws + 524288, 0, 524288, stream);
    hipMemsetAsync(bar, 0, 32768, stream);

    hipFuncSetAttribute((const void*)k_rnn, hipFuncAttributeMaxDynamicSharedMemorySize, 147456);

    // K1: input projection for all timesteps, into d_out (doubles as pre0)
    k_pre0<<<2048, 256, 0, stream>>>(x, Wi0, bi0, out);

    // K2: persistent 3-role pipeline (192 WGs, 144KB LDS -> 1/CU, co-resident)
    k_rnn<<<192, 256, 147456, stream>>>(Wr0, Wi1, Wr1, bi1, bm0, bm1, out, st, qb, bar);
}